// Round 13
// baseline (75.720 us; speedup 1.0000x reference)
//
#include <hip/hip_runtime.h>
#include <math.h>
#include <stdint.h>

#define T_TOK 8192
#define DDIM  4096
#define NEXP  64
#define TOPK  8
#define BK    64        // k per step (2 kt-chunks of 32)
#define STEPS (DDIM / BK)   // 64
#define RS    2048.0f

typedef __attribute__((ext_vector_type(8))) _Float16 half8;
typedef __attribute__((ext_vector_type(4))) float f32x4;
typedef __attribute__((address_space(3))) uint32_t lds_u32;
typedef const __attribute__((address_space(1))) uint32_t glb_u32;

// ---- K0: pack gate_weight [E][D] f32 into MFMA B-fragment order, split f16.
// chunk: wpk + kt*4096 + (n*2+p)*512 + lane*8 ; p=0: h0, p=1: (w-h0)*2048.
// B frag (16x16x32): expert col = n*16 + (lane&15), k = kt*32 + (lane>>4)*8 + j.
__global__ __launch_bounds__(256) void pack_w(
    const float* __restrict__ gw, _Float16* __restrict__ wpk)
{
    const int g    = blockIdx.x * 256 + threadIdx.x;
    const int lane = g & 63;
    const int n    = (g >> 6) & 3;
    const int kt   = g >> 8;                     // 0..127
    const int e    = n * 16 + (lane & 15);
    const int k    = kt * 32 + (lane >> 4) * 8;

    const float* src = gw + (size_t)e * DDIM + k;
    float4 v0 = *reinterpret_cast<const float4*>(src);
    float4 v1 = *reinterpret_cast<const float4*>(src + 4);
    const float v[8] = {v0.x, v0.y, v0.z, v0.w, v1.x, v1.y, v1.z, v1.w};

    half8 h0, h1;
    #pragma unroll
    for (int j = 0; j < 8; j++) {
        _Float16 a = (_Float16)v[j];
        h0[j] = a;
        h1[j] = (_Float16)((v[j] - (float)a) * RS);
    }
    _Float16* dst = wpk + (size_t)kt * 4096 + (size_t)(n * 2) * 512 + lane * 8;
    *reinterpret_cast<half8*>(dst)       = h0;
    *reinterpret_cast<half8*>(dst + 512) = h1;
}

// ---- K1: fully fused. Block = 16 tokens x 64 experts x FULL K. ----
// 256 thr = 4 waves, wave wv owns N-frag wv (16 experts), all 16 tokens.
// No K-split -> no partials, no second kernel.  Per step (BK=64):
// stage A (4 KB, src slot-swizzled c^row) + B (16 KB, linear) via
// global_load_lds into 3-buffer ring; counted vmcnt(5); raw s_barrier.
// Epilogue: logits -> LDS red[16][64], sigmoid + top-8 in block.
__global__ __launch_bounds__(256, 2) void gemm_topk(
    const float* __restrict__ x, const _Float16* __restrict__ wpk,
    const float* __restrict__ bias, float* __restrict__ out)
{
    __shared__ float    Ab[3][16 * 16 * 4];      // 3 x 4 KB  (16 rows x 16 f4-slots)
    __shared__ _Float16 Bb[3][8192];             // 3 x 16 KB (2 kt-chunks)

    const int tid  = threadIdx.x;
    const int lane = tid & 63;
    const int wv   = tid >> 6;                   // N-frag (0..3)
    const int tok0 = blockIdx.x * 16;
    const int am   = lane & 15;                  // token row / expert col
    const int ag   = lane >> 4;                  // k-group (0..3)

    // staging map: A row = wv*4 + (lane>>4), src col4 = (lane&15) ^ row
    const int s_row = wv * 4 + ag;
    const int s_c   = am;

#define STAGE(buf_, t_) do {                                                   \
        /* A: 16 rows x 64 floats, involution swizzle at 16B slots */          \
        __builtin_amdgcn_global_load_lds(                                      \
            (glb_u32*)(x + (size_t)(tok0 + s_row) * DDIM + (t_) * BK           \
                         + ((s_c ^ s_row) * 4)),                               \
            (lds_u32*)(&Ab[buf_][tid * 4]), 16, 0, 0);                         \
        /* B: 16 KB chunk (kt = 2t, 2t+1), linear */                           \
        const _Float16* bs_ = wpk + (size_t)(t_) * 8192 + wv * 2048 + lane * 8;\
        __builtin_amdgcn_global_load_lds(                                      \
            (glb_u32*)(bs_),        (lds_u32*)(&Bb[buf_][wv * 2048 + lane * 8]),        16, 0, 0); \
        __builtin_amdgcn_global_load_lds(                                      \
            (glb_u32*)(bs_ + 512),  (lds_u32*)(&Bb[buf_][wv * 2048 + 512 + lane * 8]),  16, 0, 0); \
        __builtin_amdgcn_global_load_lds(                                      \
            (glb_u32*)(bs_ + 1024), (lds_u32*)(&Bb[buf_][wv * 2048 + 1024 + lane * 8]), 16, 0, 0); \
        __builtin_amdgcn_global_load_lds(                                      \
            (glb_u32*)(bs_ + 1536), (lds_u32*)(&Bb[buf_][wv * 2048 + 1536 + lane * 8]), 16, 0, 0); \
    } while (0)

    f32x4 accH = {0.f, 0.f, 0.f, 0.f};
    f32x4 accM = {0.f, 0.f, 0.f, 0.f};

    // prologue: two stages in flight (5 loads each per thread)
    STAGE(0, 0);
    STAGE(1, 1);

    int cur = 0;
    for (int t = 0; t < STEPS; t++) {
        if (t + 1 < STEPS) asm volatile("s_waitcnt vmcnt(5)" ::: "memory");
        else               asm volatile("s_waitcnt vmcnt(0)" ::: "memory");
        __builtin_amdgcn_sched_barrier(0);
        __builtin_amdgcn_s_barrier();            // buf `cur` ready for all waves
        __builtin_amdgcn_sched_barrier(0);

        if (t + 2 < STEPS) {
            const int stg = (cur >= 1) ? cur - 1 : 2;   // (cur+2)%3
            STAGE(stg, t + 2);
        }

        // ---- compute step t from buf `cur` ----
        #pragma unroll
        for (int ktl = 0; ktl < 2; ktl++) {
            // B frags (per-lane linear 16B -> conflict-free)
            const int nb = ktl * 4096 + wv * 1024 + lane * 8;
            half8 B0 = *reinterpret_cast<const half8*>(&Bb[cur][nb]);
            half8 B1 = *reinterpret_cast<const half8*>(&Bb[cur][nb + 512]);
            // A frag: row=am, k slots (ktl*8+ag*2+h) ^ am  (2-way banks = free)
            const int s0 = (ktl * 8 + ag * 2 + 0) ^ am;
            const int s1 = (ktl * 8 + ag * 2 + 1) ^ am;
            float4 alo = *reinterpret_cast<const float4*>(&Ab[cur][am * 64 + s0 * 4]);
            float4 ahi = *reinterpret_cast<const float4*>(&Ab[cur][am * 64 + s1 * 4]);
            const float vv[8] = {alo.x, alo.y, alo.z, alo.w,
                                 ahi.x, ahi.y, ahi.z, ahi.w};
            half8 a0, a1;
            #pragma unroll
            for (int j = 0; j < 8; j++) {
                float v = vv[j];
                _Float16 h = (_Float16)v;
                a0[j] = h;
                a1[j] = (_Float16)((v - (float)h) * RS);
            }
            accH = __builtin_amdgcn_mfma_f32_16x16x32_f16(a0, B0, accH, 0, 0, 0);
            accM = __builtin_amdgcn_mfma_f32_16x16x32_f16(a0, B1, accM, 0, 0, 0);
            accM = __builtin_amdgcn_mfma_f32_16x16x32_f16(a1, B0, accM, 0, 0, 0);
        }
        cur = (cur == 2) ? 0 : cur + 1;
    }
#undef STAGE

    __syncthreads();                             // all ring reads done

    // ---- logits -> LDS red[16][64] (overlay Ab) ----
    // C/D layout (m89): col = lane&15 (expert), row = (lane>>4)*4 + r (token)
    float* red = &Ab[0][0];
    {
        const float i1 = 1.0f / RS;
        #pragma unroll
        for (int r = 0; r < 4; r++)
            red[(size_t)(ag * 4 + r) * 64 + wv * 16 + am]
                = accH[r] + accM[r] * i1;
    }
    __syncthreads();

    // ---- top-8: wave wv handles tokens wv*4 .. wv*4+3; lane = expert ----
    const float bsv = bias[lane];
    #pragma unroll
    for (int ti = 0; ti < 4; ti++) {
        const int tk = wv * 4 + ti;
        float logit  = red[(size_t)tk * 64 + lane];
        float score  = 1.f / (1.f + expf(-logit));
        float biased = score + bsv;
        float my_sc = 0.f; int my_idx = 0; float ssum = 0.f;
        #pragma unroll
        for (int j = 0; j < TOPK; j++) {
            float vb = biased; int ib = lane;
            #pragma unroll
            for (int off = 32; off >= 1; off >>= 1) {
                float ov = __shfl_xor(vb, off);
                int   oi = __shfl_xor(ib, off);
                if (ov > vb || (ov == vb && oi < ib)) { vb = ov; ib = oi; }
            }
            float s_sel = __shfl(score, ib);
            ssum += s_sel;
            if (lane == j) { my_idx = ib; my_sc = s_sel; }
            if (lane == ib) biased = -INFINITY;
        }
        if (lane < TOPK) {
            out[(size_t)(tok0 + tk) * TOPK + lane] = (float)my_idx;           // indices as f32
            out[(size_t)T_TOK * TOPK + (size_t)(tok0 + tk) * TOPK + lane]
                = my_sc / (ssum + 1e-20f);                                    // weights
        }
    }
}

extern "C" void kernel_launch(void* const* d_in, const int* in_sizes, int n_in,
                              void* d_out, int out_size, void* d_ws, size_t ws_size,
                              hipStream_t stream) {
    (void)in_sizes; (void)n_in; (void)out_size; (void)ws_size;
    const float* x    = (const float*)d_in[0];
    const float* gw   = (const float*)d_in[1];
    const float* bias = (const float*)d_in[2];
    float* out = (float*)d_out;
    _Float16* wpk = (_Float16*)d_ws;             // 1 MiB packed W frags

    pack_w<<<128, 256, 0, stream>>>(gw, wpk);
    gemm_topk<<<T_TOK / 16, 256, 0, stream>>>(x, wpk, bias, out);
}